// Round 11
// baseline (344.174 us; speedup 1.0000x reference)
//
#include <hip/hip_runtime.h>
#include <hip/hip_bf16.h>

#define IN_F   4096
#define OUT_F  4096
#define NTOK   8192
#define LRANK  128

typedef unsigned short u16;
typedef unsigned int u32;
typedef __attribute__((ext_vector_type(8))) __bf16 bf16x8;
typedef __attribute__((ext_vector_type(4))) float f32x4;

__device__ __forceinline__ u16 f2bf(float f) {
  union { float f; unsigned u; } a; a.f = f;
  return (u16)((a.u + 0x7fffu + ((a.u >> 16) & 1u)) >> 16);
}
__device__ __forceinline__ float bf2f(u16 b) {
  union { unsigned u; float f; } a; a.u = (u32)b << 16;
  return a.f;
}

// async global->LDS, 16B per lane. LDS dest is wave-uniform base + lane*16.
__device__ __forceinline__ void async_ld16(const void* g, void* l) {
  __builtin_amdgcn_global_load_lds(
      (__attribute__((address_space(1))) void*)(unsigned long long)g,
      (__attribute__((address_space(3))) void*)(unsigned int)(unsigned long long)l,
      16, 0, 0);
}

// ---------------- prep kernels ----------------

// merged small converts (L1, L2)
__global__ void cvt_bf16_2_kernel(const float* __restrict__ s1, u16* __restrict__ d1, int n1,
                                  const float* __restrict__ s2, u16* __restrict__ d2, int n2) {
  int i = blockIdx.x * blockDim.x + threadIdx.x;
  const float* s; u16* d; int j;
  if (i < n1) { s = s1; d = d1; j = i; }
  else if (i < n1 + n2) { s = s2; d = d2; j = i - n1; }
  else return;
  float4 v = ((const float4*)s)[j];
  ushort4 o;
  o.x = f2bf(v.x); o.y = f2bf(v.y); o.z = f2bf(v.z); o.w = f2bf(v.w);
  ((ushort4*)d)[j] = o;
}

__global__ void dequant_kernel(const int* __restrict__ zm, const float* __restrict__ cb,
                               const float* __restrict__ gs, const float* __restrict__ gb,
                               u16* __restrict__ W) {
  int idx = blockIdx.x * blockDim.x + threadIdx.x;   // one thread per 4 weights
  if (idx >= OUT_F * IN_F / 4) return;
  int o = idx >> 10;
  int i = (idx & 1023) << 2;
  int row = ((o >> 6) << 6) + (i >> 6);
  const int* zp = zm + ((size_t)row << 12) + ((o & 63) << 6) + (i & 63);
  int4 z = *(const int4*)zp;
  const float* cr = cb + ((size_t)row << 8);
  int g = (o >> 3) * (IN_F / 8) + (i >> 3);
  float s = gs[g], b = gb[g];
  ushort4 w;
  w.x = f2bf(b + cr[z.x] * s);
  w.y = f2bf(b + cr[z.y] * s);
  w.z = f2bf(b + cr[z.z] * s);
  w.w = f2bf(b + cr[z.w] * s);
  *(ushort4*)(W + (size_t)idx * 4) = w;
}

// ---------------- hid GEMM, K-split x8, fused input conversion, prefetch ----------------

__device__ __forceinline__ void stage_tile_128x32(const u16* __restrict__ g, int stride,
                                                  int row0, int col0,
                                                  u16* lbase, int wave, int lane) {
#pragma unroll
  for (int p = 0; p < 2; ++p) {
    int li_base = wave * 64 + p * 256;
    int li = li_base + lane;
    const u16* gaddr = g + (size_t)(row0 + (li >> 2)) * stride + col0 + ((li & 3) << 3);
    async_ld16(gaddr, lbase + li_base * 8);
  }
}

__global__ __launch_bounds__(256) void hid_part(const float* __restrict__ input,
                                                u16* __restrict__ A,
                                                const u16* __restrict__ L1,
                                                float* __restrict__ Hp) {
  __shared__ __align__(16) u16 lds[2 * 128 * 32];
  u16* ldsA = lds;
  u16* ldsB = lds + 128 * 32;

  int tid = threadIdx.x;
  int wave = tid >> 6, lane = tid & 63;
  int kc  = blockIdx.x & 7;
  int bm0 = (blockIdx.x >> 3) * 128;
  int kbase = kc * 512;
  int wr = (wave >> 1) * 64, wc = (wave & 1) * 64;
  int lrow = lane & 15, lk = (lane >> 4) * 8;

  const int crow = tid >> 1;
  const int c16  = (tid & 1) * 16;

  f32x4 acc[4][4];
#pragma unroll
  for (int m = 0; m < 4; ++m)
#pragma unroll
    for (int n = 0; n < 4; ++n)
#pragma unroll
      for (int v = 0; v < 4; ++v) acc[m][n][v] = 0.f;

  const float* ip = input + (size_t)(bm0 + crow) * IN_F + kbase + c16;
  float4 v0 = ((const float4*)ip)[0];
  float4 v1 = ((const float4*)ip)[1];
  float4 v2 = ((const float4*)ip)[2];
  float4 v3 = ((const float4*)ip)[3];

  for (int kt = 0; kt < 16; ++kt) {
    int k0 = kbase + kt * 32;

    stage_tile_128x32(L1, IN_F, 0, k0, ldsB, wave, lane);

    {
      ushort4 o0, o1, o2, o3;
      o0.x = f2bf(v0.x); o0.y = f2bf(v0.y); o0.z = f2bf(v0.z); o0.w = f2bf(v0.w);
      o1.x = f2bf(v1.x); o1.y = f2bf(v1.y); o1.z = f2bf(v1.z); o1.w = f2bf(v1.w);
      o2.x = f2bf(v2.x); o2.y = f2bf(v2.y); o2.z = f2bf(v2.z); o2.w = f2bf(v2.w);
      o3.x = f2bf(v3.x); o3.y = f2bf(v3.y); o3.z = f2bf(v3.z); o3.w = f2bf(v3.w);
      u16* lp = &ldsA[crow * 32 + c16];
      ((ushort4*)lp)[0] = o0; ((ushort4*)lp)[1] = o1;
      ((ushort4*)lp)[2] = o2; ((ushort4*)lp)[3] = o3;
      u16* gp = A + (size_t)(bm0 + crow) * IN_F + k0 + c16;
      ((ushort4*)gp)[0] = o0; ((ushort4*)gp)[1] = o1;
      ((ushort4*)gp)[2] = o2; ((ushort4*)gp)[3] = o3;
    }

    if (kt < 15) {
      ip += 32;
      v0 = ((const float4*)ip)[0];
      v1 = ((const float4*)ip)[1];
      v2 = ((const float4*)ip)[2];
      v3 = ((const float4*)ip)[3];
    }
    __syncthreads();

    bf16x8 af[4], bfr[4];
#pragma unroll
    for (int m = 0; m < 4; ++m)
      af[m] = *(const bf16x8*)&ldsA[(wr + m * 16 + lrow) * 32 + lk];
#pragma unroll
    for (int n = 0; n < 4; ++n)
      bfr[n] = *(const bf16x8*)&ldsB[(wc + n * 16 + lrow) * 32 + lk];
#pragma unroll
    for (int m = 0; m < 4; ++m)
#pragma unroll
      for (int n = 0; n < 4; ++n)
        acc[m][n] = __builtin_amdgcn_mfma_f32_16x16x32_bf16(af[m], bfr[n], acc[m][n], 0, 0, 0);
    __syncthreads();
  }

  float* Hpk = Hp + (size_t)kc * NTOK * LRANK;
  int lrow4 = (lane >> 4) * 4;
#pragma unroll
  for (int m = 0; m < 4; ++m)
#pragma unroll
    for (int n = 0; n < 4; ++n)
#pragma unroll
      for (int v = 0; v < 4; ++v) {
        int rg = bm0 + wr + m * 16 + lrow4 + v;
        int cg = wc + n * 16 + lrow;
        Hpk[(size_t)rg * LRANK + cg] = acc[m][n][v];
      }
}

__global__ void hid_reduce(const float* __restrict__ Hp, u16* __restrict__ H) {
  int i = blockIdx.x * blockDim.x + threadIdx.x;   // one thread per 4 elems
  if (i >= NTOK * LRANK / 4) return;
  const size_t stride = (size_t)NTOK * LRANK;
  float4 a0 = ((const float4*)Hp)[i];
#pragma unroll
  for (int p = 1; p < 8; ++p) {
    float4 ap = ((const float4*)(Hp + p * stride))[i];
    a0.x += ap.x; a0.y += ap.y; a0.z += ap.z; a0.w += ap.w;
  }
  ushort4 o;
  o.x = f2bf(a0.x); o.y = f2bf(a0.y); o.z = f2bf(a0.z); o.w = f2bf(a0.w);
  ((ushort4*)H)[i] = o;
}

// ---------------- main GEMM: 256x256 tile, BK=64, 8-phase schedule ----------------
// K-loop ledger identical to verified rounds 6-9. PHASE_MID no longer forces
// lgkmcnt(0): ds_reads are compiler-tracked loads, so hipcc emits fine-grained
// lgkmcnt(N) interleaved with the MFMAs (m97 behavior) -> early MFMAs start
// while late reads land. Buffer-readiness ordering is still enforced by the
// "memory"-clobbered vmcnt asm at PHASE_END_VM (reads can't hoist across it).

#define MFMA_QUAD(mh, nh)                                                        \
  _Pragma("unroll") for (int mf = 0; mf < 4; ++mf)                               \
  _Pragma("unroll") for (int nf = 0; nf < 2; ++nf)                               \
  _Pragma("unroll") for (int ks = 0; ks < 2; ++ks)                               \
    acc[(mh)*4 + mf][(nh)*2 + nf] = __builtin_amdgcn_mfma_f32_16x16x32_bf16(     \
        af[mf][ks], bfr[nh][nf][ks], acc[(mh)*4 + mf][(nh)*2 + nf], 0, 0, 0);

#define PHASE_MID                                          \
  __builtin_amdgcn_s_barrier();                            \
  __builtin_amdgcn_s_setprio(1);

#define PHASE_END                                          \
  __builtin_amdgcn_s_setprio(0);                           \
  __builtin_amdgcn_s_barrier();

#define PHASE_END_VM                                       \
  __builtin_amdgcn_s_setprio(0);                           \
  asm volatile("s_waitcnt vmcnt(4)" ::: "memory");         \
  __builtin_amdgcn_s_barrier();

#define PHASE_END_VM0                                      \
  __builtin_amdgcn_s_setprio(0);                           \
  asm volatile("s_waitcnt vmcnt(0)" ::: "memory");         \
  __builtin_amdgcn_s_barrier();

// LDS regions (bytes): buf b at b*65536; A halves +0,+16384; B halves +32768,+49152
#define LAB(b, h) ((char*)lds + (b) * 65536 + (h) * 16384)
#define LBB(b, h) ((char*)lds + (b) * 65536 + 32768 + (h) * 16384)

#define STG_K(gbase, lreg) do {                               \
    async_ld16((gbase) + gK0, (lreg) + ldst0);                \
    async_ld16((gbase) + gK1, (lreg) + ldst0 + 8192); } while (0)
#define STG_L(gbase, lreg) do {                               \
    async_ld16((gbase) + gL0, (lreg) + ldst0);                \
    async_ld16((gbase) + gL1, (lreg) + ldst0 + 8192); } while (0)

#define LDF(p, byteoff, lb) (*(const bf16x8*)((p) + (byteoff) + (lb)))

__global__ __launch_bounds__(512)
__attribute__((amdgpu_waves_per_eu(2, 2)))
void gemm_main(const u16* __restrict__ A,
               const u16* __restrict__ W,
               const u16* __restrict__ H,
               const u16* __restrict__ L2,
               const float* __restrict__ scale,
               const float* __restrict__ bias,
               float* __restrict__ out) {
  __shared__ __align__(16) u16 lds[65536];   // 128 KiB

  const int tid = threadIdx.x;
  const int lane = tid & 63, wave = tid >> 6;
  const int wg_m = wave >> 2;
  const int lr = lane & 15;

  // bijective XCD swizzle (nwg=512, 512%8==0)
  int bid = blockIdx.x;
  int swz = (bid & 7) * 64 + (bid >> 3);
  const int bn0 = (swz & 15) * 256;
  const int bm0 = (swz >> 4) * 256;

  // per-lane staging constants
  const int row_c = tid >> 3;
  const int xslot = ((tid & 7) ^ (row_c & 7)) << 3;
  const int gK0 = row_c * IN_F + xslot;
  const int gK1 = gK0 + 64 * IN_F;
  const int ldst0 = (tid & ~63) * 16;

  // per-lane frag-read constants
  const int lb0 = (lr << 7) | ((((lane >> 4)) ^ (lr & 7)) << 4);
  const int lb1 = (lr << 7) | (((4 | (lane >> 4)) ^ (lr & 7)) << 4);

  const u16* baseA0 = A + (size_t)bm0 * IN_F;
  const u16* baseA1 = A + (size_t)(bm0 + 128) * IN_F;
  const u16* baseW0 = W + (size_t)bn0 * IN_F;
  const u16* baseW1 = W + (size_t)(bn0 + 128) * IN_F;

  const int wg_n = wave & 3;
  const int b_row0 = (wg_n & 1) * 64;
  const char* pA0 = LAB(0, wg_m);
  const char* pA1 = LAB(1, wg_m);
  const char* pB0 = LBB(0, wg_n >> 1) + b_row0 * 128;
  const char* pB1 = LBB(1, wg_n >> 1) + b_row0 * 128;

  f32x4 acc[8][4];
#pragma unroll
  for (int m = 0; m < 8; ++m)
#pragma unroll
    for (int n = 0; n < 4; ++n)
#pragma unroll
      for (int v = 0; v < 4; ++v) acc[m][n][v] = 0.f;

  // ---- prologue: kt0 -> buf0 (B0,B1,A0,A1), kt1.B -> buf1 ----
  STG_K(baseW0, LBB(0, 0));
  STG_K(baseW1, LBB(0, 1));
  STG_K(baseA0, LAB(0, 0));
  STG_K(baseA1, LAB(0, 1));
  STG_K(baseW0 + 64, LBB(1, 0));
  STG_K(baseW1 + 64, LBB(1, 1));
  asm volatile("s_waitcnt vmcnt(4)" ::: "memory");
  __builtin_amdgcn_s_barrier();

  bf16x8 af[4][2];
  bf16x8 bfr[2][2][2];

  for (int u = 0; u < 31; ++u) {
    const int c1k = (2 * u + 1) * 64;
    const int n0k = (2 * u + 2) * 64;
    const int n1k = (2 * u + 3) * 64;

    // ---- P1: quad(0,0) on buf0 ----
#pragma unroll
    for (int mf = 0; mf < 4; ++mf) {
      af[mf][0] = LDF(pA0, mf * 2048, lb0);
      af[mf][1] = LDF(pA0, mf * 2048, lb1);
    }
#pragma unroll
    for (int nf = 0; nf < 2; ++nf) {
      bfr[0][nf][0] = LDF(pB0, nf * 2048, lb0);
      bfr[0][nf][1] = LDF(pB0, nf * 2048, lb1);
    }
    STG_K(baseA0 + c1k, LAB(1, 0));
    PHASE_MID; MFMA_QUAD(0, 0); PHASE_END;

    // ---- P2: quad(0,1) ----
#pragma unroll
    for (int nf = 0; nf < 2; ++nf) {
      bfr[1][nf][0] = LDF(pB0, 4096 + nf * 2048, lb0);
      bfr[1][nf][1] = LDF(pB0, 4096 + nf * 2048, lb1);
    }
    STG_K(baseA1 + c1k, LAB(1, 1));
    PHASE_MID; MFMA_QUAD(0, 1); PHASE_END;

    // ---- P3: quad(1,1) ----
#pragma unroll
    for (int mf = 0; mf < 4; ++mf) {
      af[mf][0] = LDF(pA0, 8192 + mf * 2048, lb0);
      af[mf][1] = LDF(pA0, 8192 + mf * 2048, lb1);
    }
    STG_K(baseW0 + n0k, LBB(0, 0));
    PHASE_MID; MFMA_QUAD(1, 1); PHASE_END;

    // ---- P4: quad(1,0) ----
    STG_K(baseW1 + n0k, LBB(0, 1));
    PHASE_MID; MFMA_QUAD(1, 0); PHASE_END_VM;

    // ---- P5: quad(0,0) on buf1 ----
#pragma unroll
    for (int mf = 0; mf < 4; ++mf) {
      af[mf][0] = LDF(pA1, mf * 2048, lb0);
      af[mf][1] = LDF(pA1, mf * 2048, lb1);
    }
#pragma unroll
    for (int nf = 0; nf < 2; ++nf) {
      bfr[0][nf][0] = LDF(pB1, nf * 2048, lb0);
      bfr[0][nf][1] = LDF(pB1, nf * 2048, lb1);
    }
    STG_K(baseA0 + n0k, LAB(0, 0));
    PHASE_MID; MFMA_QUAD(0, 0); PHASE_END;

    // ---- P6: quad(0,1) ----
#pragma unroll
    for (int nf = 0; nf < 2; ++nf) {
      bfr[1][nf][0] = LDF(pB1, 4096 + nf * 2048, lb0);
      bfr[1][nf][1] = LDF(pB1, 4096 + nf * 2048, lb1);
    }
    STG_K(baseA1 + n0k, LAB(0, 1));
    PHASE_MID; MFMA_QUAD(0, 1); PHASE_END;

    // ---- P7: quad(1,1) ----
#pragma unroll
    for (int mf = 0; mf < 4; ++mf) {
      af[mf][0] = LDF(pA1, 8192 + mf * 2048, lb0);
      af[mf][1] = LDF(pA1, 8192 + mf * 2048, lb1);
    }
    STG_K(baseW0 + n1k, LBB(1, 0));
    PHASE_MID; MFMA_QUAD(1, 1); PHASE_END;

    // ---- P8: quad(1,0) ----
    STG_K(baseW1 + n1k, LBB(1, 1));
    PHASE_MID; MFMA_QUAD(1, 0); PHASE_END_VM;
  }

  // ---- peeled tail (u=31): only buf1.A (kt63) staged; no next-tile loads ----
  {
    const int c1k = 63 * 64;

    // P1
#pragma unroll
    for (int mf = 0; mf < 4; ++mf) {
      af[mf][0] = LDF(pA0, mf * 2048, lb0);
      af[mf][1] = LDF(pA0, mf * 2048, lb1);
    }
#pragma unroll
    for (int nf = 0; nf < 2; ++nf) {
      bfr[0][nf][0] = LDF(pB0, nf * 2048, lb0);
      bfr[0][nf][1] = LDF(pB0, nf * 2048, lb1);
    }
    STG_K(baseA0 + c1k, LAB(1, 0));
    PHASE_MID; MFMA_QUAD(0, 0); PHASE_END;

    // P2
#pragma unroll
    for (int nf = 0; nf < 2; ++nf) {
      bfr[1][nf][0] = LDF(pB0, 4096 + nf * 2048, lb0);
      bfr[1][nf][1] = LDF(pB0, 4096 + nf * 2048, lb1);
    }
    STG_K(baseA1 + c1k, LAB(1, 1));
    PHASE_MID; MFMA_QUAD(0, 1); PHASE_END;

    // P3
#pragma unroll
    for (int mf = 0; mf < 4; ++mf) {
      af[mf][0] = LDF(pA0, 8192 + mf * 2048, lb0);
      af[mf][1] = LDF(pA0, 8192 + mf * 2048, lb1);
    }
    PHASE_MID; MFMA_QUAD(1, 1); PHASE_END;

    // P4: only 4 loads outstanding -> drain fully before buf1.A reads
    PHASE_MID; MFMA_QUAD(1, 0); PHASE_END_VM0;

    // P5
#pragma unroll
    for (int mf = 0; mf < 4; ++mf) {
      af[mf][0] = LDF(pA1, mf * 2048, lb0);
      af[mf][1] = LDF(pA1, mf * 2048, lb1);
    }
#pragma unroll
    for (int nf = 0; nf < 2; ++nf) {
      bfr[0][nf][0] = LDF(pB1, nf * 2048, lb0);
      bfr[0][nf][1] = LDF(pB1, nf * 2048, lb1);
    }
    PHASE_MID; MFMA_QUAD(0, 0); PHASE_END;

    // P6
#pragma unroll
    for (int nf = 0; nf < 2; ++nf) {
      bfr[1][nf][0] = LDF(pB1, 4096 + nf * 2048, lb0);
      bfr[1][nf][1] = LDF(pB1, 4096 + nf * 2048, lb1);
    }
    PHASE_MID; MFMA_QUAD(0, 1); PHASE_END;

    // P7
#pragma unroll
    for (int mf = 0; mf < 4; ++mf) {
      af[mf][0] = LDF(pA1, 8192 + mf * 2048, lb0);
      af[mf][1] = LDF(pA1, 8192 + mf * 2048, lb1);
    }
    PHASE_MID; MFMA_QUAD(1, 1); PHASE_END;

    // P8
    PHASE_MID; MFMA_QUAD(1, 0); PHASE_END;
  }

  // ---- pack baseline to bf16 in-register: acc(128 regs) -> pk(64 regs) ----
  uint2 pk[8][4];
#pragma unroll
  for (int mf = 0; mf < 8; ++mf)
#pragma unroll
    for (int nf = 0; nf < 4; ++nf) {
      pk[mf][nf].x = (u32)f2bf(acc[mf][nf][0]) | ((u32)f2bf(acc[mf][nf][1]) << 16);
      pk[mf][nf].y = (u32)f2bf(acc[mf][nf][2]) | ((u32)f2bf(acc[mf][nf][3]) << 16);
    }

  // ---- fused low-rank epilogue ----
  float scl[4], bs_[4];
#pragma unroll
  for (int nf = 0; nf < 4; ++nf) {
    int cg = bn0 + wg_n * 64 + nf * 16 + lr;
    scl[nf] = scale[cg];
    bs_[nf] = bias[cg];
  }

  const int gL0 = row_c * LRANK + xslot;
  const int gL1 = gL0 + 64 * LRANK;

  // drain K-loop stages, then stage H (64KB) + L2m (64KB)
  asm volatile("s_waitcnt vmcnt(0)" ::: "memory");
  __builtin_amdgcn_s_barrier();
  {
    const u16* baseH0 = H + (size_t)bm0 * LRANK;
    const u16* baseH1 = H + (size_t)(bm0 + 128) * LRANK;
    const u16* baseL0 = L2 + (size_t)bn0 * LRANK;
    const u16* baseL1 = L2 + (size_t)(bn0 + 128) * LRANK;
    STG_L(baseH0,      (char*)lds + 0);
    STG_L(baseH1,      (char*)lds + 16384);
    STG_L(baseH0 + 64, (char*)lds + 32768);
    STG_L(baseH1 + 64, (char*)lds + 49152);
    STG_L(baseL0,      (char*)lds + 65536);
    STG_L(baseL1,      (char*)lds + 81920);
    STG_L(baseL0 + 64, (char*)lds + 98304);
    STG_L(baseL1 + 64, (char*)lds + 114688);
  }
  asm volatile("s_waitcnt vmcnt(0)" ::: "memory");
  __builtin_amdgcn_s_barrier();

  const char* pH = (char*)lds + wg_m * 16384;
  const char* pL = (char*)lds + 65536 + (wg_n >> 1) * 16384 + (wg_n & 1) * 8192;

  // multiplicative pass, [2][4] chunks: pk <- pack((maccM+scale)*unpack(pk))
#pragma unroll
  for (int mq = 0; mq < 4; ++mq) {
    f32x4 macc[2][4];
#pragma unroll
    for (int m = 0; m < 2; ++m)
#pragma unroll
      for (int n = 0; n < 4; ++n)
#pragma unroll
        for (int v = 0; v < 4; ++v) macc[m][n][v] = 0.f;
#pragma unroll
    for (int kc = 0; kc < 4; ++kc) {
      const int sb = (kc >> 1) * 32768;
      const int lb = (kc & 1) ? lb1 : lb0;
      bf16x8 lf[4];
#pragma unroll
      for (int nf = 0; nf < 4; ++nf)
        lf[nf] = LDF(pL + sb, nf * 2048, lb);
#pragma unroll
      for (int mf = 0; mf < 2; ++mf) {
        bf16x8 hf = LDF(pH + sb, (mq * 2 + mf) * 2048, lb);
#pragma unroll
        for (int nf = 0; nf < 4; ++nf)
          macc[mf][nf] = __builtin_amdgcn_mfma_f32_16x16x32_bf16(hf, lf[nf], macc[mf][nf], 0, 0, 0);
      }
    }
#pragma unroll
    for (int mf = 0; mf < 2; ++mf)
#pragma unroll
      for (int nf = 0; nf < 4; ++nf) {
        int m8 = mq * 2 + mf;
        uint2 p = pk[m8][nf];
        float t0 = (macc[mf][nf][0] + scl[nf]) * bf2f((u16)(p.x & 0xffff));
        float t1 = (macc[mf][nf][1] + scl[nf]) * bf2f((u16)(p.x >> 16));
        float t2 = (macc[mf][nf][2] + scl[nf]) * bf2f((u16)(p.y & 0xffff));
        float t3 = (macc[mf][nf][3] + scl[nf]) * bf2f((u16)(p.y >> 16));
        p.x = (u32)f2bf(t0) | ((u32)f2bf(t1) << 16);
        p.y = (u32)f2bf(t2) | ((u32)f2bf(t3) << 16);
        pk[m8][nf] = p;
      }
  }

  // restage L2 additive rows over L2m
  __builtin_amdgcn_s_barrier();
  {
    const u16* baseL0 = L2 + (size_t)(OUT_F + bn0) * LRANK;
    const u16* baseL1 = L2 + (size_t)(OUT_F + bn0 + 128) * LRANK;
    STG_L(baseL0,      (char*)lds + 65536);
    STG_L(baseL1,      (char*)lds + 81920);
    STG_L(baseL0 + 64, (char*)lds + 98304);
    STG_L(baseL1 + 64, (char*)lds + 114688);
  }
  asm volatile("s_waitcnt vmcnt(0)" ::: "memory");
  __builtin_amdgcn_s_barrier();

  // additive pass, [2][4] chunks: out = unpack(pk) + maccA + bias
#pragma unroll
  for (int mq = 0; mq < 4; ++mq) {
    f32x4 macc[2][4];
#pragma unroll
    for (int m = 0; m < 2; ++m)
#pragma unroll
      for (int n = 0; n < 4; ++n)
#pragma unroll
        for (int v = 0; v < 4; ++v) macc[m][n][v] = 0.f;
#pragma unroll
    for (int kc = 0; kc < 4; ++kc) {
      const int sb = (kc >> 1) * 32768;
      const int lb = (kc & 1) ? lb1 : lb0;
      bf16x8 lf[4];
#pragma unroll
      for (int nf = 0; nf < 4; ++nf)
        lf[nf] = LDF(pL + sb, nf * 2048, lb);
#pragma unroll
      for (int mf = 0; mf < 2; ++mf) {
        bf16x8 hf = LDF(pH + sb, (mq * 2 + mf) * 2048, lb);
#pragma unroll
        for (int nf = 0; nf < 4; ++nf)
          macc[mf][nf] = __builtin_amdgcn_mfma_f32_16x16x32_bf16(hf, lf[nf], macc[mf][nf], 0, 0, 0);
      }
    }
#pragma unroll
    for (int mf = 0; mf < 2; ++mf)
#pragma unroll
      for (int nf = 0; nf < 4; ++nf) {
        int m8 = mq * 2 + mf;
        uint2 p = pk[m8][nf];
        int rg = bm0 + wg_m * 128 + m8 * 16 + (lane >> 4) * 4;
        int cg = bn0 + wg_n * 64 + nf * 16 + lr;
        float* op = out + (size_t)rg * OUT_F + cg;
        op[0 * OUT_F] = bf2f((u16)(p.x & 0xffff)) + macc[mf][nf][0] + bs_[nf];
        op[1 * OUT_F] = bf2f((u16)(p.x >> 16))    + macc[mf][nf][1] + bs_[nf];
        op[2 * OUT_F] = bf2f((u16)(p.y & 0xffff)) + macc[mf][nf][2] + bs_[nf];
        op[3 * OUT_F] = bf2f((u16)(p.y >> 16))    + macc[mf][nf][3] + bs_[nf];
      }
  }
}

// ---------------- launch ----------------

extern "C" void kernel_launch(void* const* d_in, const int* in_sizes, int n_in,
                              void* d_out, int out_size, void* d_ws, size_t ws_size,
                              hipStream_t stream) {
  const float* input = (const float*)d_in[0];
  const int*   zm    = (const int*)d_in[1];
  const float* cb    = (const float*)d_in[2];
  const float* l1    = (const float*)d_in[3];
  const float* l2    = (const float*)d_in[4];
  const float* gs    = (const float*)d_in[5];
  const float* gb    = (const float*)d_in[6];
  const float* scale = (const float*)d_in[7];
  const float* bias  = (const float*)d_in[8];
  float* out = (float*)d_out;

  const size_t OFF_A  = 0;                                        // 64 MiB
  const size_t OFF_W  = OFF_A + (size_t)NTOK * IN_F * 2;          // 32 MiB
  const size_t OFF_L1 = OFF_W + (size_t)OUT_F * IN_F * 2;         // 1 MiB
  const size_t OFF_L2 = OFF_L1 + (size_t)LRANK * IN_F * 2;        // 2 MiB
  const size_t OFF_H  = OFF_L2 + (size_t)2 * OUT_F * LRANK * 2;   // 2 MiB
  const size_t OFF_HP = OFF_H + (size_t)NTOK * LRANK * 2;         // 32 MiB (f32 partials x8)
  const size_t NEED   = OFF_HP + (size_t)8 * NTOK * LRANK * 4;
  if (ws_size < NEED) return;

  char* ws = (char*)d_ws;
  u16* A    = (u16*)(ws + OFF_A);
  u16* W    = (u16*)(ws + OFF_W);
  u16* L1b  = (u16*)(ws + OFF_L1);
  u16* L2b  = (u16*)(ws + OFF_L2);
  u16* H    = (u16*)(ws + OFF_H);
  float* Hp = (float*)(ws + OFF_HP);

  cvt_bf16_2_kernel<<<((LRANK * IN_F + 2 * OUT_F * LRANK) / 4 + 255) / 256, 256, 0, stream>>>(
      l1, L1b, LRANK * IN_F / 4, l2, L2b, 2 * OUT_F * LRANK / 4);
  dequant_kernel<<<(OUT_F * IN_F / 4) / 256, 256, 0, stream>>>(zm, cb, gs, gb, W);

  hid_part<<<8 * (NTOK / 128), 256, 0, stream>>>(input, A, L1b, Hp);
  hid_reduce<<<(NTOK * LRANK / 4) / 256, 256, 0, stream>>>(Hp, H);

  gemm_main<<<(NTOK / 256) * (OUT_F / 256), 512, 0, stream>>>(A, W, H, L2b, scale, bias, out);
}

// Round 12
// 334.854 us; speedup vs baseline: 1.0278x; 1.0278x over previous
//
#include <hip/hip_runtime.h>
#include <hip/hip_bf16.h>

#define IN_F   4096
#define OUT_F  4096
#define NTOK   8192
#define LRANK  128

typedef unsigned short u16;
typedef unsigned int u32;
typedef __attribute__((ext_vector_type(8))) __bf16 bf16x8;
typedef __attribute__((ext_vector_type(4))) float f32x4;

__device__ __forceinline__ u16 f2bf(float f) {
  union { float f; unsigned u; } a; a.f = f;
  return (u16)((a.u + 0x7fffu + ((a.u >> 16) & 1u)) >> 16);
}
__device__ __forceinline__ float bf2f(u16 b) {
  union { unsigned u; float f; } a; a.u = (u32)b << 16;
  return a.f;
}

// async global->LDS, 16B per lane. LDS dest is wave-uniform base + lane*16.
__device__ __forceinline__ void async_ld16(const void* g, void* l) {
  __builtin_amdgcn_global_load_lds(
      (__attribute__((address_space(1))) void*)(unsigned long long)g,
      (__attribute__((address_space(3))) void*)(unsigned int)(unsigned long long)l,
      16, 0, 0);
}

// ---------------- prep: dequant + small converts, one launch ----------------

#define DQ_BLOCKS (OUT_F * IN_F / 4 / 256)   // 16384

__global__ void prep_kernel(const int* __restrict__ zm, const float* __restrict__ cb,
                            const float* __restrict__ gs, const float* __restrict__ gb,
                            u16* __restrict__ W,
                            const float* __restrict__ s1, u16* __restrict__ d1, int n1,
                            const float* __restrict__ s2, u16* __restrict__ d2, int n2) {
  int b = blockIdx.x;
  if (b < DQ_BLOCKS) {
    int idx = b * 256 + threadIdx.x;           // one thread per 4 weights
    int o = idx >> 10;
    int i = (idx & 1023) << 2;
    int row = ((o >> 6) << 6) + (i >> 6);
    const int* zp = zm + ((size_t)row << 12) + ((o & 63) << 6) + (i & 63);
    int4 z = *(const int4*)zp;
    const float* cr = cb + ((size_t)row << 8);
    int g = (o >> 3) * (IN_F / 8) + (i >> 3);
    float s = gs[g], bb = gb[g];
    ushort4 w;
    w.x = f2bf(bb + cr[z.x] * s);
    w.y = f2bf(bb + cr[z.y] * s);
    w.z = f2bf(bb + cr[z.z] * s);
    w.w = f2bf(bb + cr[z.w] * s);
    *(ushort4*)(W + (size_t)idx * 4) = w;
  } else {
    int i = (b - DQ_BLOCKS) * 256 + threadIdx.x;
    const float* s; u16* d; int j;
    if (i < n1) { s = s1; d = d1; j = i; }
    else if (i < n1 + n2) { s = s2; d = d2; j = i - n1; }
    else return;
    float4 v = ((const float4*)s)[j];
    ushort4 o;
    o.x = f2bf(v.x); o.y = f2bf(v.y); o.z = f2bf(v.z); o.w = f2bf(v.w);
    ((ushort4*)d)[j] = o;
  }
}

// ---------------- hid GEMM, K-split x8, fused input conversion, prefetch ----------------

__device__ __forceinline__ void stage_tile_128x32(const u16* __restrict__ g, int stride,
                                                  int row0, int col0,
                                                  u16* lbase, int wave, int lane) {
#pragma unroll
  for (int p = 0; p < 2; ++p) {
    int li_base = wave * 64 + p * 256;
    int li = li_base + lane;
    const u16* gaddr = g + (size_t)(row0 + (li >> 2)) * stride + col0 + ((li & 3) << 3);
    async_ld16(gaddr, lbase + li_base * 8);
  }
}

__global__ __launch_bounds__(256) void hid_part(const float* __restrict__ input,
                                                u16* __restrict__ A,
                                                const u16* __restrict__ L1,
                                                u16* __restrict__ Hp) {
  __shared__ __align__(16) u16 lds[2 * 128 * 32];
  u16* ldsA = lds;
  u16* ldsB = lds + 128 * 32;

  int tid = threadIdx.x;
  int wave = tid >> 6, lane = tid & 63;
  int kc  = blockIdx.x & 7;
  int bm0 = (blockIdx.x >> 3) * 128;
  int kbase = kc * 512;
  int wr = (wave >> 1) * 64, wc = (wave & 1) * 64;
  int lrow = lane & 15, lk = (lane >> 4) * 8;

  const int crow = tid >> 1;
  const int c16  = (tid & 1) * 16;

  f32x4 acc[4][4];
#pragma unroll
  for (int m = 0; m < 4; ++m)
#pragma unroll
    for (int n = 0; n < 4; ++n)
#pragma unroll
      for (int v = 0; v < 4; ++v) acc[m][n][v] = 0.f;

  const float* ip = input + (size_t)(bm0 + crow) * IN_F + kbase + c16;
  float4 v0 = ((const float4*)ip)[0];
  float4 v1 = ((const float4*)ip)[1];
  float4 v2 = ((const float4*)ip)[2];
  float4 v3 = ((const float4*)ip)[3];

  for (int kt = 0; kt < 16; ++kt) {
    int k0 = kbase + kt * 32;

    stage_tile_128x32(L1, IN_F, 0, k0, ldsB, wave, lane);

    {
      ushort4 o0, o1, o2, o3;
      o0.x = f2bf(v0.x); o0.y = f2bf(v0.y); o0.z = f2bf(v0.z); o0.w = f2bf(v0.w);
      o1.x = f2bf(v1.x); o1.y = f2bf(v1.y); o1.z = f2bf(v1.z); o1.w = f2bf(v1.w);
      o2.x = f2bf(v2.x); o2.y = f2bf(v2.y); o2.z = f2bf(v2.z); o2.w = f2bf(v2.w);
      o3.x = f2bf(v3.x); o3.y = f2bf(v3.y); o3.z = f2bf(v3.z); o3.w = f2bf(v3.w);
      u16* lp = &ldsA[crow * 32 + c16];
      ((ushort4*)lp)[0] = o0; ((ushort4*)lp)[1] = o1;
      ((ushort4*)lp)[2] = o2; ((ushort4*)lp)[3] = o3;
      u16* gp = A + (size_t)(bm0 + crow) * IN_F + k0 + c16;
      ((ushort4*)gp)[0] = o0; ((ushort4*)gp)[1] = o1;
      ((ushort4*)gp)[2] = o2; ((ushort4*)gp)[3] = o3;
    }

    if (kt < 15) {
      ip += 32;
      v0 = ((const float4*)ip)[0];
      v1 = ((const float4*)ip)[1];
      v2 = ((const float4*)ip)[2];
      v3 = ((const float4*)ip)[3];
    }
    __syncthreads();

    bf16x8 af[4], bfr[4];
#pragma unroll
    for (int m = 0; m < 4; ++m)
      af[m] = *(const bf16x8*)&ldsA[(wr + m * 16 + lrow) * 32 + lk];
#pragma unroll
    for (int n = 0; n < 4; ++n)
      bfr[n] = *(const bf16x8*)&ldsB[(wc + n * 16 + lrow) * 32 + lk];
#pragma unroll
    for (int m = 0; m < 4; ++m)
#pragma unroll
      for (int n = 0; n < 4; ++n)
        acc[m][n] = __builtin_amdgcn_mfma_f32_16x16x32_bf16(af[m], bfr[n], acc[m][n], 0, 0, 0);
    __syncthreads();
  }

  // bf16 partials: partial-rounding error ~= H's own bf16 rounding, well under threshold
  u16* Hpk = Hp + (size_t)kc * NTOK * LRANK;
  int lrow4 = (lane >> 4) * 4;
#pragma unroll
  for (int m = 0; m < 4; ++m)
#pragma unroll
    for (int n = 0; n < 4; ++n)
#pragma unroll
      for (int v = 0; v < 4; ++v) {
        int rg = bm0 + wr + m * 16 + lrow4 + v;
        int cg = wc + n * 16 + lrow;
        Hpk[(size_t)rg * LRANK + cg] = f2bf(acc[m][n][v]);
      }
}

__global__ void hid_reduce(const u16* __restrict__ Hp, u16* __restrict__ H) {
  int i = blockIdx.x * blockDim.x + threadIdx.x;   // one thread per 4 elems
  if (i >= NTOK * LRANK / 4) return;
  const size_t stride = (size_t)NTOK * LRANK;
  float s0 = 0.f, s1 = 0.f, s2 = 0.f, s3 = 0.f;
#pragma unroll
  for (int p = 0; p < 8; ++p) {
    ushort4 u = ((const ushort4*)(Hp + p * stride))[i];
    s0 += bf2f(u.x); s1 += bf2f(u.y); s2 += bf2f(u.z); s3 += bf2f(u.w);
  }
  ushort4 o;
  o.x = f2bf(s0); o.y = f2bf(s1); o.z = f2bf(s2); o.w = f2bf(s3);
  ((ushort4*)H)[i] = o;
}

// ---------------- main GEMM: 256x256 tile, BK=64, 8-phase schedule ----------------
// K-loop ledger identical to verified rounds 6-10. XCD swizzle now 8m x 8n
// per XCD (32 MB working set vs 40) for better L2 capture of staging loads.

#define MFMA_QUAD(mh, nh)                                                        \
  _Pragma("unroll") for (int mf = 0; mf < 4; ++mf)                               \
  _Pragma("unroll") for (int nf = 0; nf < 2; ++nf)                               \
  _Pragma("unroll") for (int ks = 0; ks < 2; ++ks)                               \
    acc[(mh)*4 + mf][(nh)*2 + nf] = __builtin_amdgcn_mfma_f32_16x16x32_bf16(     \
        af[mf][ks], bfr[nh][nf][ks], acc[(mh)*4 + mf][(nh)*2 + nf], 0, 0, 0);

#define PHASE_MID                                          \
  __builtin_amdgcn_s_barrier();                            \
  __builtin_amdgcn_s_setprio(1);

#define PHASE_END                                          \
  __builtin_amdgcn_s_setprio(0);                           \
  __builtin_amdgcn_s_barrier();

#define PHASE_END_VM                                       \
  __builtin_amdgcn_s_setprio(0);                           \
  asm volatile("s_waitcnt vmcnt(4)" ::: "memory");         \
  __builtin_amdgcn_s_barrier();

#define PHASE_END_VM0                                      \
  __builtin_amdgcn_s_setprio(0);                           \
  asm volatile("s_waitcnt vmcnt(0)" ::: "memory");         \
  __builtin_amdgcn_s_barrier();

// LDS regions (bytes): buf b at b*65536; A halves +0,+16384; B halves +32768,+49152
#define LAB(b, h) ((char*)lds + (b) * 65536 + (h) * 16384)
#define LBB(b, h) ((char*)lds + (b) * 65536 + 32768 + (h) * 16384)

#define STG_K(gbase, lreg) do {                               \
    async_ld16((gbase) + gK0, (lreg) + ldst0);                \
    async_ld16((gbase) + gK1, (lreg) + ldst0 + 8192); } while (0)
#define STG_L(gbase, lreg) do {                               \
    async_ld16((gbase) + gL0, (lreg) + ldst0);                \
    async_ld16((gbase) + gL1, (lreg) + ldst0 + 8192); } while (0)

#define LDF(p, byteoff, lb) (*(const bf16x8*)((p) + (byteoff) + (lb)))

__global__ __launch_bounds__(512)
__attribute__((amdgpu_waves_per_eu(2, 2)))
void gemm_main(const u16* __restrict__ A,
               const u16* __restrict__ W,
               const u16* __restrict__ H,
               const u16* __restrict__ L2,
               const float* __restrict__ scale,
               const float* __restrict__ bias,
               float* __restrict__ out) {
  __shared__ __align__(16) u16 lds[65536];   // 128 KiB

  const int tid = threadIdx.x;
  const int lane = tid & 63, wave = tid >> 6;
  const int wg_m = wave >> 2;
  const int lr = lane & 15;

  // XCD swizzle: xcd x owns an 8m x 8n block region (bijective: 32m x 16n grid)
  int bid = blockIdx.x;
  int x = bid & 7, w = bid >> 3;
  const int bm0 = (((x >> 1) << 3) + (w >> 3)) * 256;
  const int bn0 = (((x & 1) << 3) + (w & 7)) * 256;

  // per-lane staging constants
  const int row_c = tid >> 3;
  const int xslot = ((tid & 7) ^ (row_c & 7)) << 3;
  const int gK0 = row_c * IN_F + xslot;
  const int gK1 = gK0 + 64 * IN_F;
  const int ldst0 = (tid & ~63) * 16;

  // per-lane frag-read constants
  const int lb0 = (lr << 7) | ((((lane >> 4)) ^ (lr & 7)) << 4);
  const int lb1 = (lr << 7) | (((4 | (lane >> 4)) ^ (lr & 7)) << 4);

  const u16* baseA0 = A + (size_t)bm0 * IN_F;
  const u16* baseA1 = A + (size_t)(bm0 + 128) * IN_F;
  const u16* baseW0 = W + (size_t)bn0 * IN_F;
  const u16* baseW1 = W + (size_t)(bn0 + 128) * IN_F;

  const int wg_n = wave & 3;
  const int b_row0 = (wg_n & 1) * 64;
  const char* pA0 = LAB(0, wg_m);
  const char* pA1 = LAB(1, wg_m);
  const char* pB0 = LBB(0, wg_n >> 1) + b_row0 * 128;
  const char* pB1 = LBB(1, wg_n >> 1) + b_row0 * 128;

  f32x4 acc[8][4];
#pragma unroll
  for (int m = 0; m < 8; ++m)
#pragma unroll
    for (int n = 0; n < 4; ++n)
#pragma unroll
      for (int v = 0; v < 4; ++v) acc[m][n][v] = 0.f;

  // ---- prologue: kt0 -> buf0 (B0,B1,A0,A1), kt1.B -> buf1 ----
  STG_K(baseW0, LBB(0, 0));
  STG_K(baseW1, LBB(0, 1));
  STG_K(baseA0, LAB(0, 0));
  STG_K(baseA1, LAB(0, 1));
  STG_K(baseW0 + 64, LBB(1, 0));
  STG_K(baseW1 + 64, LBB(1, 1));
  asm volatile("s_waitcnt vmcnt(4)" ::: "memory");
  __builtin_amdgcn_s_barrier();

  bf16x8 af[4][2];
  bf16x8 bfr[2][2][2];

  for (int u = 0; u < 31; ++u) {
    const int c1k = (2 * u + 1) * 64;
    const int n0k = (2 * u + 2) * 64;
    const int n1k = (2 * u + 3) * 64;

    // ---- P1: quad(0,0) on buf0 ----
#pragma unroll
    for (int mf = 0; mf < 4; ++mf) {
      af[mf][0] = LDF(pA0, mf * 2048, lb0);
      af[mf][1] = LDF(pA0, mf * 2048, lb1);
    }
#pragma unroll
    for (int nf = 0; nf < 2; ++nf) {
      bfr[0][nf][0] = LDF(pB0, nf * 2048, lb0);
      bfr[0][nf][1] = LDF(pB0, nf * 2048, lb1);
    }
    STG_K(baseA0 + c1k, LAB(1, 0));
    PHASE_MID; MFMA_QUAD(0, 0); PHASE_END;

    // ---- P2: quad(0,1) ----
#pragma unroll
    for (int nf = 0; nf < 2; ++nf) {
      bfr[1][nf][0] = LDF(pB0, 4096 + nf * 2048, lb0);
      bfr[1][nf][1] = LDF(pB0, 4096 + nf * 2048, lb1);
    }
    STG_K(baseA1 + c1k, LAB(1, 1));
    PHASE_MID; MFMA_QUAD(0, 1); PHASE_END;

    // ---- P3: quad(1,1) ----
#pragma unroll
    for (int mf = 0; mf < 4; ++mf) {
      af[mf][0] = LDF(pA0, 8192 + mf * 2048, lb0);
      af[mf][1] = LDF(pA0, 8192 + mf * 2048, lb1);
    }
    STG_K(baseW0 + n0k, LBB(0, 0));
    PHASE_MID; MFMA_QUAD(1, 1); PHASE_END;

    // ---- P4: quad(1,0) ----
    STG_K(baseW1 + n0k, LBB(0, 1));
    PHASE_MID; MFMA_QUAD(1, 0); PHASE_END_VM;

    // ---- P5: quad(0,0) on buf1 ----
#pragma unroll
    for (int mf = 0; mf < 4; ++mf) {
      af[mf][0] = LDF(pA1, mf * 2048, lb0);
      af[mf][1] = LDF(pA1, mf * 2048, lb1);
    }
#pragma unroll
    for (int nf = 0; nf < 2; ++nf) {
      bfr[0][nf][0] = LDF(pB1, nf * 2048, lb0);
      bfr[0][nf][1] = LDF(pB1, nf * 2048, lb1);
    }
    STG_K(baseA0 + n0k, LAB(0, 0));
    PHASE_MID; MFMA_QUAD(0, 0); PHASE_END;

    // ---- P6: quad(0,1) ----
#pragma unroll
    for (int nf = 0; nf < 2; ++nf) {
      bfr[1][nf][0] = LDF(pB1, 4096 + nf * 2048, lb0);
      bfr[1][nf][1] = LDF(pB1, 4096 + nf * 2048, lb1);
    }
    STG_K(baseA1 + n0k, LAB(0, 1));
    PHASE_MID; MFMA_QUAD(0, 1); PHASE_END;

    // ---- P7: quad(1,1) ----
#pragma unroll
    for (int mf = 0; mf < 4; ++mf) {
      af[mf][0] = LDF(pA1, 8192 + mf * 2048, lb0);
      af[mf][1] = LDF(pA1, 8192 + mf * 2048, lb1);
    }
    STG_K(baseW0 + n1k, LBB(1, 0));
    PHASE_MID; MFMA_QUAD(1, 1); PHASE_END;

    // ---- P8: quad(1,0) ----
    STG_K(baseW1 + n1k, LBB(1, 1));
    PHASE_MID; MFMA_QUAD(1, 0); PHASE_END_VM;
  }

  // ---- peeled tail (u=31): only buf1.A (kt63) staged; no next-tile loads ----
  {
    const int c1k = 63 * 64;

    // P1
#pragma unroll
    for (int mf = 0; mf < 4; ++mf) {
      af[mf][0] = LDF(pA0, mf * 2048, lb0);
      af[mf][1] = LDF(pA0, mf * 2048, lb1);
    }
#pragma unroll
    for (int nf = 0; nf < 2; ++nf) {
      bfr[0][nf][0] = LDF(pB0, nf * 2048, lb0);
      bfr[0][nf][1] = LDF(pB0, nf * 2048, lb1);
    }
    STG_K(baseA0 + c1k, LAB(1, 0));
    PHASE_MID; MFMA_QUAD(0, 0); PHASE_END;

    // P2
#pragma unroll
    for (int nf = 0; nf < 2; ++nf) {
      bfr[1][nf][0] = LDF(pB0, 4096 + nf * 2048, lb0);
      bfr[1][nf][1] = LDF(pB0, 4096 + nf * 2048, lb1);
    }
    STG_K(baseA1 + c1k, LAB(1, 1));
    PHASE_MID; MFMA_QUAD(0, 1); PHASE_END;

    // P3
#pragma unroll
    for (int mf = 0; mf < 4; ++mf) {
      af[mf][0] = LDF(pA0, 8192 + mf * 2048, lb0);
      af[mf][1] = LDF(pA0, 8192 + mf * 2048, lb1);
    }
    PHASE_MID; MFMA_QUAD(1, 1); PHASE_END;

    // P4: only 4 loads outstanding -> drain fully before buf1.A reads
    PHASE_MID; MFMA_QUAD(1, 0); PHASE_END_VM0;

    // P5
#pragma unroll
    for (int mf = 0; mf < 4; ++mf) {
      af[mf][0] = LDF(pA1, mf * 2048, lb0);
      af[mf][1] = LDF(pA1, mf * 2048, lb1);
    }
#pragma unroll
    for (int nf = 0; nf < 2; ++nf) {
      bfr[0][nf][0] = LDF(pB1, nf * 2048, lb0);
      bfr[0][nf][1] = LDF(pB1, nf * 2048, lb1);
    }
    PHASE_MID; MFMA_QUAD(0, 0); PHASE_END;

    // P6
#pragma unroll
    for (int nf = 0; nf < 2; ++nf) {
      bfr[1][nf][0] = LDF(pB1, 4096 + nf * 2048, lb0);
      bfr[1][nf][1] = LDF(pB1, 4096 + nf * 2048, lb1);
    }
    PHASE_MID; MFMA_QUAD(0, 1); PHASE_END;

    // P7
#pragma unroll
    for (int mf = 0; mf < 4; ++mf) {
      af[mf][0] = LDF(pA1, 8192 + mf * 2048, lb0);
      af[mf][1] = LDF(pA1, 8192 + mf * 2048, lb1);
    }
    PHASE_MID; MFMA_QUAD(1, 1); PHASE_END;

    // P8
    PHASE_MID; MFMA_QUAD(1, 0); PHASE_END;
  }

  // ---- pack baseline to bf16 in-register: acc(128 regs) -> pk(64 regs) ----
  uint2 pk[8][4];
#pragma unroll
  for (int mf = 0; mf < 8; ++mf)
#pragma unroll
    for (int nf = 0; nf < 4; ++nf) {
      pk[mf][nf].x = (u32)f2bf(acc[mf][nf][0]) | ((u32)f2bf(acc[mf][nf][1]) << 16);
      pk[mf][nf].y = (u32)f2bf(acc[mf][nf][2]) | ((u32)f2bf(acc[mf][nf][3]) << 16);
    }

  // ---- fused low-rank epilogue ----
  float scl[4], bs_[4];
#pragma unroll
  for (int nf = 0; nf < 4; ++nf) {
    int cg = bn0 + wg_n * 64 + nf * 16 + lr;
    scl[nf] = scale[cg];
    bs_[nf] = bias[cg];
  }

  const int gL0 = row_c * LRANK + xslot;
  const int gL1 = gL0 + 64 * LRANK;

  // stage H (64KB) + L2m (64KB)
  asm volatile("s_waitcnt vmcnt(0)" ::: "memory");
  __builtin_amdgcn_s_barrier();
  {
    const u16* baseH0 = H + (size_t)bm0 * LRANK;
    const u16* baseH1 = H + (size_t)(bm0 + 128) * LRANK;
    const u16* baseL0 = L2 + (size_t)bn0 * LRANK;
    const u16* baseL1 = L2 + (size_t)(bn0 + 128) * LRANK;
    STG_L(baseH0,      (char*)lds + 0);
    STG_L(baseH1,      (char*)lds + 16384);
    STG_L(baseH0 + 64, (char*)lds + 32768);
    STG_L(baseH1 + 64, (char*)lds + 49152);
    STG_L(baseL0,      (char*)lds + 65536);
    STG_L(baseL1,      (char*)lds + 81920);
    STG_L(baseL0 + 64, (char*)lds + 98304);
    STG_L(baseL1 + 64, (char*)lds + 114688);
  }
  asm volatile("s_waitcnt vmcnt(0)" ::: "memory");
  __builtin_amdgcn_s_barrier();

  const char* pH = (char*)lds + wg_m * 16384;
  const char* pL = (char*)lds + 65536 + (wg_n >> 1) * 16384 + (wg_n & 1) * 8192;

  // multiplicative pass, [2][4] chunks: pk <- pack((maccM+scale)*unpack(pk))
#pragma unroll
  for (int mq = 0; mq < 4; ++mq) {
    f32x4 macc[2][4];
#pragma unroll
    for (int m = 0; m < 2; ++m)
#pragma unroll
      for (int n = 0; n < 4; ++n)
#pragma unroll
        for (int v = 0; v < 4; ++v) macc[m][n][v] = 0.f;
#pragma unroll
    for (int kc = 0; kc < 4; ++kc) {
      const int sb = (kc >> 1) * 32768;
      const int lb = (kc & 1) ? lb1 : lb0;
      bf16x8 lf[4];
#pragma unroll
      for (int nf = 0; nf < 4; ++nf)
        lf[nf] = LDF(pL + sb, nf * 2048, lb);
#pragma unroll
      for (int mf = 0; mf < 2; ++mf) {
        bf16x8 hf = LDF(pH + sb, (mq * 2 + mf) * 2048, lb);
#pragma unroll
        for (int nf = 0; nf < 4; ++nf)
          macc[mf][nf] = __builtin_amdgcn_mfma_f32_16x16x32_bf16(hf, lf[nf], macc[mf][nf], 0, 0, 0);
      }
    }
#pragma unroll
    for (int mf = 0; mf < 2; ++mf)
#pragma unroll
      for (int nf = 0; nf < 4; ++nf) {
        int m8 = mq * 2 + mf;
        uint2 p = pk[m8][nf];
        float t0 = (macc[mf][nf][0] + scl[nf]) * bf2f((u16)(p.x & 0xffff));
        float t1 = (macc[mf][nf][1] + scl[nf]) * bf2f((u16)(p.x >> 16));
        float t2 = (macc[mf][nf][2] + scl[nf]) * bf2f((u16)(p.y & 0xffff));
        float t3 = (macc[mf][nf][3] + scl[nf]) * bf2f((u16)(p.y >> 16));
        p.x = (u32)f2bf(t0) | ((u32)f2bf(t1) << 16);
        p.y = (u32)f2bf(t2) | ((u32)f2bf(t3) << 16);
        pk[m8][nf] = p;
      }
  }

  // restage L2 additive rows over L2m
  __builtin_amdgcn_s_barrier();
  {
    const u16* baseL0 = L2 + (size_t)(OUT_F + bn0) * LRANK;
    const u16* baseL1 = L2 + (size_t)(OUT_F + bn0 + 128) * LRANK;
    STG_L(baseL0,      (char*)lds + 65536);
    STG_L(baseL1,      (char*)lds + 81920);
    STG_L(baseL0 + 64, (char*)lds + 98304);
    STG_L(baseL1 + 64, (char*)lds + 114688);
  }
  asm volatile("s_waitcnt vmcnt(0)" ::: "memory");
  __builtin_amdgcn_s_barrier();

  // additive pass, [2][4] chunks: out = unpack(pk) + maccA + bias
#pragma unroll
  for (int mq = 0; mq < 4; ++mq) {
    f32x4 macc[2][4];
#pragma unroll
    for (int m = 0; m < 2; ++m)
#pragma unroll
      for (int n = 0; n < 4; ++n)
#pragma unroll
        for (int v = 0; v < 4; ++v) macc[m][n][v] = 0.f;
#pragma unroll
    for (int kc = 0; kc < 4; ++kc) {
      const int sb = (kc >> 1) * 32768;
      const int lb = (kc & 1) ? lb1 : lb0;
      bf16x8 lf[4];
#pragma unroll
      for (int nf = 0; nf < 4; ++nf)
        lf[nf] = LDF(pL + sb, nf * 2048, lb);
#pragma unroll
      for (int mf = 0; mf < 2; ++mf) {
        bf16x8 hf = LDF(pH + sb, (mq * 2 + mf) * 2048, lb);
#pragma unroll
        for (int nf = 0; nf < 4; ++nf)
          macc[mf][nf] = __builtin_amdgcn_mfma_f32_16x16x32_bf16(hf, lf[nf], macc[mf][nf], 0, 0, 0);
      }
    }
#pragma unroll
    for (int mf = 0; mf < 2; ++mf)
#pragma unroll
      for (int nf = 0; nf < 4; ++nf) {
        int m8 = mq * 2 + mf;
        uint2 p = pk[m8][nf];
        int rg = bm0 + wg_m * 128 + m8 * 16 + (lane >> 4) * 4;
        int cg = bn0 + wg_n * 64 + nf * 16 + lr;
        float* op = out + (size_t)rg * OUT_F + cg;
        op[0 * OUT_F] = bf2f((u16)(p.x & 0xffff)) + macc[mf][nf][0] + bs_[nf];
        op[1 * OUT_F] = bf2f((u16)(p.x >> 16))    + macc[mf][nf][1] + bs_[nf];
        op[2 * OUT_F] = bf2f((u16)(p.y & 0xffff)) + macc[mf][nf][2] + bs_[nf];
        op[3 * OUT_F] = bf2f((u16)(p.y >> 16))    + macc[mf][nf][3] + bs_[nf];
      }
  }
}

// ---------------- launch ----------------

extern "C" void kernel_launch(void* const* d_in, const int* in_sizes, int n_in,
                              void* d_out, int out_size, void* d_ws, size_t ws_size,
                              hipStream_t stream) {
  const float* input = (const float*)d_in[0];
  const int*   zm    = (const int*)d_in[1];
  const float* cb    = (const float*)d_in[2];
  const float* l1    = (const float*)d_in[3];
  const float* l2    = (const float*)d_in[4];
  const float* gs    = (const float*)d_in[5];
  const float* gb    = (const float*)d_in[6];
  const float* scale = (const float*)d_in[7];
  const float* bias  = (const float*)d_in[8];
  float* out = (float*)d_out;

  const size_t OFF_A  = 0;                                        // 64 MiB
  const size_t OFF_W  = OFF_A + (size_t)NTOK * IN_F * 2;          // 32 MiB
  const size_t OFF_L1 = OFF_W + (size_t)OUT_F * IN_F * 2;         // 1 MiB
  const size_t OFF_L2 = OFF_L1 + (size_t)LRANK * IN_F * 2;        // 2 MiB
  const size_t OFF_H  = OFF_L2 + (size_t)2 * OUT_F * LRANK * 2;   // 2 MiB
  const size_t OFF_HP = OFF_H + (size_t)NTOK * LRANK * 2;         // 16 MiB (bf16 partials x8)
  const size_t NEED   = OFF_HP + (size_t)8 * NTOK * LRANK * 2;
  if (ws_size < NEED) return;

  char* ws = (char*)d_ws;
  u16* A    = (u16*)(ws + OFF_A);
  u16* W    = (u16*)(ws + OFF_W);
  u16* L1b  = (u16*)(ws + OFF_L1);
  u16* L2b  = (u16*)(ws + OFF_L2);
  u16* H    = (u16*)(ws + OFF_H);
  u16* Hp   = (u16*)(ws + OFF_HP);

  const int n1 = LRANK * IN_F / 4;
  const int n2 = 2 * OUT_F * LRANK / 4;
  const int cvt_blocks = (n1 + n2 + 255) / 256;
  prep_kernel<<<DQ_BLOCKS + cvt_blocks, 256, 0, stream>>>(
      zm, cb, gs, gb, W, l1, L1b, n1, l2, L2b, n2);

  hid_part<<<8 * (NTOK / 128), 256, 0, stream>>>(input, A, L1b, Hp);
  hid_reduce<<<(NTOK * LRANK / 4) / 256, 256, 0, stream>>>(Hp, H);

  gemm_main<<<(NTOK / 256) * (OUT_F / 256), 512, 0, stream>>>(A, W, H, L2b, scale, bias, out);
}